// Round 6
// baseline (230.805 us; speedup 1.0000x reference)
//
#include <hip/hip_runtime.h>
#include <math.h>

#define Bn 4
#define Cn 256
#define Hn 64
#define Wn 64
#define On 256
#define HWn 4096
#define Pn 16384   // B*H*W
#define Kc 2304    // 9*256

// s_waitcnt imm: vmcnt=63 (no wait), expcnt=7 (no wait), lgkmcnt=0 (drain LDS)
#define LGKM0 0xc07f

typedef _Float16 half8 __attribute__((ext_vector_type(8)));
typedef float floatx4 __attribute__((ext_vector_type(4)));

// ---------------------------------------------------------------------------
// ONE init kernel: blocks 0..4095 = fp32 NCHW -> f16 NHWC transpose;
// 4096..4863 = main-weight pack (layer l = (bx-4096)>>8, n = &255);
// 4864..4959 = offset-weight pack (layer l = (bx-4864)>>5, oc = &31).
// R14: offset-weight chunk order is CHANNEL-GROUP-MAJOR (c = cw*9 + t) so
// phase 1 can stage one 64-ch window and sweep all 9 taps from it.
__global__ void k_init(const float* __restrict__ x, _Float16* __restrict__ act0,
                       const float* __restrict__ w0, const float* __restrict__ w1,
                       const float* __restrict__ w2, const float* __restrict__ wo0,
                       const float* __restrict__ wo1, const float* __restrict__ wo2,
                       _Float16* __restrict__ wtp, _Float16* __restrict__ wbop) {
  int bx = blockIdx.x;
  int tid = threadIdx.x;
  if (bx < 4096) {
    // transpose tile: R=Cn rows, Cc=HWn cols; out[b][hw][ch] = in[b][ch][hw]
    __shared__ float tile[32][33];
    int cx = bx & 127, cy = (bx >> 7) & 7, b = bx >> 10;
    int c0 = cx * 32, r0 = cy * 32;
    int tx = tid & 31, ty = tid >> 5;
    const float* ib = x + (size_t)b * Cn * HWn;
    _Float16* ob = act0 + (size_t)b * Cn * HWn;
#pragma unroll
    for (int i = 0; i < 32; i += 8)
      tile[ty + i][tx] = ib[(size_t)(r0 + ty + i) * HWn + (c0 + tx)];
    __syncthreads();
#pragma unroll
    for (int i = 0; i < 32; i += 8)
      ob[(size_t)(c0 + ty + i) * Cn + (r0 + tx)] = (_Float16)tile[tx][ty + i];
  } else if (bx < 4864) {
    int b2 = bx - 4096;
    int l = b2 >> 8;
    int n = b2 & 255;
    const float* w = (l == 0) ? w0 : (l == 1) ? w1 : w2;
    _Float16* dst = wtp + (size_t)l * 256 * Kc;
    int g = n >> 4, col = n & 15;
    int cq = tid >> 6;
    int kk = tid & 63;
    int kq = kk >> 5;
    int k32 = kk & 31;
    int quad = k32 >> 3;
    int e = k32 & 7;
    const float* src = w + (size_t)n * 2304 + (size_t)tid * 9;
#pragma unroll
    for (int t = 0; t < 9; ++t) {
      int c = t * 4 + cq;
      size_t d = ((size_t)((c * 16 + g) * 2 + kq)) * 512 + (quad * 16 + col) * 8 + e;
      dst[d] = (_Float16)src[t];
    }
  } else {
    int b3 = bx - 4864;
    int l = b3 >> 5;
    int n = b3 & 31;
    const float* w = (l == 0) ? wo0 : (l == 1) ? wo1 : wo2;
    _Float16* dst = wbop + (size_t)l * 36 * 2048;
    int g = n >> 4, col = n & 15;
    int cw = tid >> 6;
    int r = tid & 63;
    int kq = r >> 5;
    int r2 = r & 31;
    int quad = r2 >> 3;
    int e = r2 & 7;
#pragma unroll
    for (int t = 0; t < 9; ++t) {
      int c = cw * 9 + t;    // R14: channel-group-major chunk order
      size_t d = ((size_t)((c * 2 + g) * 2 + kq)) * 512 + (quad * 16 + col) * 8 + e;
      dst[d] = (n < 27) ? (_Float16)w[((size_t)n * 256 + tid) * 9 + t] : (_Float16)0.f;
    }
  }
}

// ---------------------------------------------------------------------------
// FUSED layer kernel: one block = 64 pixels (one full image row), 512 threads.
// R14 phase 1: offset conv via LDS WINDOW. Diagnosis: both phases ran 36
//   identical gather/stage/barrier chunks at ~1800cy each; phase 1 (2 GF) cost
//   as much as phase 2 (19.3 GF) -> ~28us of pure overhead per layer, invariant
//   across R0-R5 because the algorithm never changed. Taps are STATIC (+-1)
//   and the tile is one full row (x0=0): stage a 3x66-px window (one 64-ch
//   group, 25.3KB, XOR-swizzled) once per channel-group, then sweep all 9 taps
//   BARRIER-FREE with MFMA A-fragments read directly from the window.
//   Phase-1 L2 traffic 295MB -> 26MB/layer; barriers 72 -> 8.
// Phase 2: best-measured R3 structure verbatim (Bs-LDS + depth-2 reg staging,
//   rolled tap loop). R9 XCD swizzle kept.
__global__ __launch_bounds__(512) void k_layer(
    const _Float16* __restrict__ xh,
    const _Float16* __restrict__ wbop, const float* __restrict__ boff,
    const _Float16* __restrict__ wtp, const float* __restrict__ bias,
    _Float16* __restrict__ outh, float* __restrict__ outf) {
  __shared__ __align__(16) _Float16 As[2][64][72];    // 18.4 KB
  __shared__ __align__(16) _Float16 Bs[2][16384];     // 64 KB
  __shared__ __align__(16) _Float16 win[3 * 66 * 64]; // 25.3 KB (phase-1 window)
  __shared__ __align__(16) float omS[64 * 33];        // 8.4 KB
  __shared__ __align__(16) float sampS[64][9][8];     // 18 KB

  int bid = blockIdx.x;
  int lb = ((bid & 7) << 5) + (bid >> 3);   // XCD-contiguous logical block
  int p0 = lb * 64;
  int tid = threadIdx.x;       // 0..511
  int lane = tid & 63;
  int wave = tid >> 6;         // 0..7
  int quad = lane >> 4;
  int col = lane & 15;

  int ar = tid >> 3;           // staging/gather row 0..63
  int aci = (tid & 7) * 8;     // 8-channel segment

  int yB = (p0 & 4095) >> 6;   // block-uniform: tile is one full image row
  int bB = p0 >> 12;

  half8 zero8;
#pragma unroll
  for (int e = 0; e < 8; ++e) zero8[e] = (_Float16)0.f;

  // ================= phase 1: offset conv (M=64,N=32,K=2304) =============
  // window sweep: for each 64-ch group cg, stage rows y-1..y+1, px -1..64
  // (66 cols, zero-padded), then 9 static taps MFMA straight from LDS.
  int mi = wave >> 1;   // 0..3 (16-row group)
  int ng = wave & 1;    // 0..1 (16-col group)

  floatx4 acc1 = (floatx4){0.f, 0.f, 0.f, 0.f};
  half8 boA[2], boB[2];   // offset-weight fragments, chunk-parity slots
#pragma unroll
  for (int kq = 0; kq < 2; ++kq) {
    boA[kq] = *(const half8*)(wbop + (size_t)(ng * 2 + kq) * 512 + lane * 8);
    boB[kq] = *(const half8*)(wbop + 2048 + (size_t)(ng * 2 + kq) * 512 + lane * 8);
  }

#pragma unroll 1
  for (int cg = 0; cg < 4; ++cg) {
    // stage window: 198 row-px x 8 segs = 1584 half8 slots
    for (int e = tid; e < 1584; e += 512) {
      int seg = e & 7;
      int rowpx = e >> 3;          // 0..197
      int r = rowpx / 66;          // 0..2
      int px = rowpx - r * 66;     // 0..65
      int yy = yB + r - 1;
      int xx = px - 1;
      half8 v = zero8;
      if (((unsigned)yy < 64u) & ((unsigned)xx < 64u))
        v = *(const half8*)(xh + ((size_t)((bB * Hn + yy) * Wn + xx)) * Cn +
                            cg * 64 + seg * 8);
      int ba = (rowpx * 128 + seg * 16) ^ ((px & 7) << 4);
      *(half8*)((char*)win + ba) = v;
    }
    __syncthreads();

#pragma unroll
    for (int t = 0; t < 9; ++t) {
      int cp = cg * 9 + t;
      int dty = t / 3;         // 0..2 (window row)
      int dtx = t % 3;         // 0..2 (window col shift; win col 0 = x-1)
#pragma unroll
      for (int kq = 0; kq < 2; ++kq) {
        int pxw = mi * 16 + col + dtx;   // 0..65
        int ba = ((dty * 66 + pxw) * 128 + kq * 64 + quad * 16) ^ ((pxw & 7) << 4);
        half8 af = *(const half8*)((const char*)win + ba);
        acc1 = __builtin_amdgcn_mfma_f32_16x16x32_f16(
            af, (cp & 1) ? boB[kq] : boA[kq], acc1, 0, 0, 0);
      }
      if (cp + 2 < 36) {     // refill consumed parity slot with chunk cp+2
        const _Float16* wob = wbop + (size_t)(cp + 2) * 2048;
#pragma unroll
        for (int kq = 0; kq < 2; ++kq) {
          half8 v2 = *(const half8*)(wob + (size_t)(ng * 2 + kq) * 512 + lane * 8);
          if (cp & 1) boB[kq] = v2; else boA[kq] = v2;
        }
      }
    }
    __syncthreads();   // before next cg overwrites win
  }

  // om -> LDS
  {
    int n1 = ng * 16 + col;
    if (n1 < 27) {
      float bb = boff[n1];
#pragma unroll
      for (int r = 0; r < 4; ++r)
        omS[(mi * 16 + quad * 4 + r) * 33 + n1] = acc1[r] + bb;
    }
  }
  __syncthreads();

  // fused coords: 64 px x 9 taps = 576 entries -> sampS (LDS)
  for (int e = tid; e < 576; e += 512) {
    int lp = e / 9;
    int k = e - lp * 9;
    int pp = p0 + lp;
    int bi = pp >> 12;
    int pyx = pp & 4095;
    int py = pyx >> 6, px = pyx & 63;

    float dy = omS[lp * 33 + 2 * k];
    float dx = omS[lp * 33 + 2 * k + 1];
    float m = 1.f / (1.f + expf(-omS[lp * 33 + 18 + k]));

    float ys = (float)(py + k / 3 - 1) + dy;
    float xs = (float)(px + k % 3 - 1) + dx;
    float y0f = floorf(ys), x0f = floorf(xs);
    float wy = ys - y0f, wx = xs - x0f;
    int y0 = (int)y0f, x0 = (int)x0f;
    int y1 = y0 + 1, x1 = x0 + 1;

    bool vy0 = (y0 >= 0) & (y0 < Hn);
    bool vy1 = (y1 >= 0) & (y1 < Hn);
    bool vx0 = (x0 >= 0) & (x0 < Wn);
    bool vx1 = (x1 >= 0) & (x1 < Wn);
    int y0c = min(max(y0, 0), Hn - 1), y1c = min(max(y1, 0), Hn - 1);
    int x0c = min(max(x0, 0), Wn - 1), x1c = min(max(x1, 0), Wn - 1);

    int base = bi * HWn;
    float* s = &sampS[lp][k][0];
    ((int*)s)[0] = (base + y0c * Wn + x0c) * Cn;
    ((int*)s)[1] = (base + y0c * Wn + x1c) * Cn;
    ((int*)s)[2] = (base + y1c * Wn + x0c) * Cn;
    ((int*)s)[3] = (base + y1c * Wn + x1c) * Cn;
    s[4] = (vy0 && vx0) ? m * (1.f - wy) * (1.f - wx) : 0.f;
    s[5] = (vy0 && vx1) ? m * (1.f - wy) * wx : 0.f;
    s[6] = (vy1 && vx0) ? m * wy * (1.f - wx) : 0.f;
    s[7] = (vy1 && vx1) ? m * wy * wx : 0.f;
  }
  __syncthreads();

  // ================= phase 2: deformable main GEMM (M=64,N=256) ==========
  // (R3 structure verbatim: Bs-LDS + depth-2 reg staging, rolled tap loop)
  int mw = wave >> 2;          // 0..1 (32-row half)
  int nw = wave & 3;           // 0..3 (64-col group)

  float bj[4];
#pragma unroll
  for (int j = 0; j < 4; ++j) bj[j] = bias[(nw * 4 + j) * 16 + col];

  floatx4 acc[2][4];
#pragma unroll
  for (int i = 0; i < 2; ++i)
#pragma unroll
    for (int j = 0; j < 4; ++j) acc[i][j] = (floatx4){0.f, 0.f, 0.f, 0.f};

  half8 g00, g01, g10, g11;
  half8 bst0[4], bst1[4];      // B staging regs, chunk-parity slots (depth-2)
  int4 ofsC, ofsN;
  float4 wvC, wvN;

  // prologue: tap0 samp; gathers for chunk 0; B chunks 0 and 1 into regs
  ofsC = *(const int4*)&sampS[ar][0][0];
  wvC = *(const float4*)&sampS[ar][0][4];
  ofsN = ofsC; wvN = wvC;
  g00 = *(const half8*)(xh + (size_t)ofsC.x + aci);
  g01 = *(const half8*)(xh + (size_t)ofsC.y + aci);
  g10 = *(const half8*)(xh + (size_t)ofsC.z + aci);
  g11 = *(const half8*)(xh + (size_t)ofsC.w + aci);
#pragma unroll
  for (int q = 0; q < 4; ++q)
    bst0[q] = *(const half8*)(wtp + (size_t)(q * 512 + tid) * 8);
#pragma unroll
  for (int q = 0; q < 4; ++q)
    bst1[q] = *(const half8*)(wtp + 16384 + (size_t)(q * 512 + tid) * 8);

#pragma unroll 1
  for (int t = 0; t < 9; ++t) {
    // next tap's samp entry (LDS; consumed at cc=3's gather issue)
    if (t < 8) {
      ofsN = *(const int4*)&sampS[ar][t + 1][0];
      wvN = *(const float4*)&sampS[ar][t + 1][4];
    }
#pragma unroll
    for (int cc = 0; cc < 4; ++cc) {          // chunk c = 4t+cc; buf = cc&1
      // 1. stage A chunk c (vm-waits the 4 gather loads only)
      {
        _Float16 h00 = (_Float16)wvC.x, h01 = (_Float16)wvC.y;
        _Float16 h10 = (_Float16)wvC.z, h11 = (_Float16)wvC.w;
        half8 r;
#pragma unroll
        for (int e = 0; e < 8; ++e)
          r[e] = g00[e] * h00 + g01[e] * h01 + g10[e] * h10 + g11[e] * h11;
        *(half8*)&As[cc & 1][ar][aci] = r;
      }
      // 2. stage B chunk c from reg slots (loaded at iter c-2; no vm wait)
#pragma unroll
      for (int q = 0; q < 4; ++q)
        *(half8*)&Bs[cc & 1][(q * 512 + tid) * 8] = (cc & 1) ? bst1[q] : bst0[q];
      // 3. issue gathers for chunk c+1 (stay in flight across barrier)
      if (cc < 3) {
        int ci = (cc + 1) * 64 + aci;
        g00 = *(const half8*)(xh + (size_t)ofsC.x + ci);
        g01 = *(const half8*)(xh + (size_t)ofsC.y + ci);
        g10 = *(const half8*)(xh + (size_t)ofsC.z + ci);
        g11 = *(const half8*)(xh + (size_t)ofsC.w + ci);
      } else if (t < 8) {
        g00 = *(const half8*)(xh + (size_t)ofsN.x + aci);
        g01 = *(const half8*)(xh + (size_t)ofsN.y + aci);
        g10 = *(const half8*)(xh + (size_t)ofsN.z + aci);
        g11 = *(const half8*)(xh + (size_t)ofsN.w + aci);
      }
      // 4. refill B slot with chunk c+2 (exists iff 4t+cc+2 <= 35)
      if (cc < 2 || t < 8) {
        const _Float16* wsrc = wtp + ((size_t)(4 * t) + cc + 2) * 16384;
#pragma unroll
        for (int q = 0; q < 4; ++q) {
          half8 v = *(const half8*)(wsrc + (size_t)(q * 512 + tid) * 8);
          if (cc & 1) bst1[q] = v; else bst0[q] = v;
        }
      }

      __builtin_amdgcn_s_waitcnt(LGKM0);   // LDS visible; vmem stays outstanding
      __builtin_amdgcn_s_barrier();

      half8 af[2][2];
#pragma unroll
      for (int kq = 0; kq < 2; ++kq)
#pragma unroll
        for (int i = 0; i < 2; ++i)
          af[kq][i] =
              *(const half8*)&As[cc & 1][mw * 32 + i * 16 + col][kq * 32 + quad * 8];

      half8 bf[2][4];
#pragma unroll
      for (int kq = 0; kq < 2; ++kq)
#pragma unroll
        for (int j = 0; j < 4; ++j)
          bf[kq][j] =
              *(const half8*)&Bs[cc & 1][((nw * 4 + j) * 2 + kq) * 512 + lane * 8];

#pragma unroll
      for (int kq = 0; kq < 2; ++kq)
#pragma unroll
        for (int i = 0; i < 2; ++i)
#pragma unroll
          for (int j = 0; j < 4; ++j)
            acc[i][j] = __builtin_amdgcn_mfma_f32_16x16x32_f16(
                af[kq][i], bf[kq][j], acc[i][j], 0, 0, 0);
    }
    ofsC = ofsN;
    wvC = wvN;
  }

  // epilogue: bias + relu. Hidden layers: f16 NHWC. Last layer: fp32 NCHW
  // direct to d_out (float4: 4 consecutive p = 4 consecutive x).
#pragma unroll
  for (int i = 0; i < 2; ++i)
#pragma unroll
    for (int j = 0; j < 4; ++j) {
      int n = (nw * 4 + j) * 16 + col;
      if (outf) {
        int pb = p0 + mw * 32 + i * 16 + quad * 4;
        int bi = pb >> 12;
        int pyx = pb & 4095;
        float4 v;
        v.x = fmaxf(acc[i][j][0] + bj[j], 0.f);
        v.y = fmaxf(acc[i][j][1] + bj[j], 0.f);
        v.z = fmaxf(acc[i][j][2] + bj[j], 0.f);
        v.w = fmaxf(acc[i][j][3] + bj[j], 0.f);
        *(float4*)(outf + ((size_t)(bi * On + n)) * HWn + pyx) = v;
      } else {
#pragma unroll
        for (int r = 0; r < 4; ++r) {
          int pp = p0 + mw * 32 + i * 16 + quad * 4 + r;
          float v = fmaxf(acc[i][j][r] + bj[j], 0.f);
          outh[(size_t)pp * On + n] = (_Float16)v;
        }
      }
    }
}

// ---------------------------------------------------------------------------
extern "C" void kernel_launch(void* const* d_in, const int* in_sizes, int n_in,
                              void* d_out, int out_size, void* d_ws, size_t ws_size,
                              hipStream_t stream) {
  (void)in_sizes; (void)n_in; (void)out_size; (void)ws_size;
  const float* x = (const float*)d_in[0];

  _Float16* act0h = (_Float16*)d_ws;                     // Pn*Cn f16
  _Float16* act1h = act0h + (size_t)Pn * Cn;             // Pn*Cn f16
  _Float16* wbop  = act1h + (size_t)Pn * Cn;             // 3*36*2048 f16
  _Float16* wtp   = wbop + (size_t)3 * 36 * 2048;        // 3*256*Kc f16

  k_init<<<4960, 256, 0, stream>>>(
      x, act0h,
      (const float*)d_in[3], (const float*)d_in[7], (const float*)d_in[11],
      (const float*)d_in[1], (const float*)d_in[5], (const float*)d_in[9],
      wtp, wbop);

  _Float16* cur = act0h;
  _Float16* nxt = act1h;
  for (int l = 0; l < 3; ++l) {
    const float* b_off = (const float*)d_in[2 + l * 4];
    const float* b     = (const float*)d_in[4 + l * 4];
    k_layer<<<Pn / 64, 512, 0, stream>>>(
        cur, wbop + (size_t)l * 36 * 2048, b_off,
        wtp + (size_t)l * 256 * Kc, b, nxt,
        (l == 2) ? (float*)d_out : nullptr);
    _Float16* tswap = cur; cur = nxt; nxt = tswap;
  }
}